// Round 1
// baseline (9200.979 us; speedup 1.0000x reference)
//
#include <hip/hip_runtime.h>
#include <math.h>

#define N_    16
#define CIN_  256
#define DIM_  32
#define H_    128
#define W_    128
#define P_    (H_*W_)          // 16384
#define A_    192
#define R_    192
#define AR_   (A_*R_)          // 36864

// ---------------- LUT: rho index per (angle, pixel), uint8 ----------------
// Matches numpy: irho = float(int(sqrt(H*H+W*W)+1))/(NUMRHO-1) = 182/191
// r = round(x'*cos(th)/irho + y'*sin(th)/irho), clip(r+96, 0, 191)
__global__ __launch_bounds__(256) void lut_kernel(unsigned char* __restrict__ lut) {
    int a = blockIdx.x;                       // 192 blocks
    double theta = (double)a * (M_PI / 192.0);
    double irho  = 182.0 / 191.0;
    double ts = sin(theta) / irho;
    double tc = cos(theta) / irho;
    for (int i = threadIdx.x; i < P_/4; i += 256) {
        int p = i * 4;
        uchar4 o;
        unsigned char rr[4];
        #pragma unroll
        for (int j = 0; j < 4; ++j) {
            int pp = p + j;
            int y = pp >> 7, x = pp & 127;
            double t1 = __dmul_rn((double)(x - 64), tc);
            double t2 = __dmul_rn((double)(y - 64), ts);
            double v  = __dadd_rn(t1, t2);
            int r = (int)rint(v) + 96;        // round half-to-even, like np.round
            r = r < 0 ? 0 : (r > 191 ? 191 : r);
            rr[j] = (unsigned char)r;
        }
        o.x = rr[0]; o.y = rr[1]; o.z = rr[2]; o.w = rr[3];
        *(uchar4*)(lut + (size_t)a * P_ + p) = o;
    }
}

// ---------------- 1x1 conv + bias: x[16,256,128,128] -> pre[16,32,128,128] -
__global__ __launch_bounds__(256) void conv1x1_kernel(
        const float* __restrict__ x, const float* __restrict__ w,
        const float* __restrict__ b, float* __restrict__ out) {
    int g = blockIdx.x * 256 + threadIdx.x;   // 0..262143  (N*P)
    int n = g >> 14, p = g & (P_ - 1);
    const float* xp = x + (size_t)n * CIN_ * P_ + p;
    float acc[DIM_];
    #pragma unroll
    for (int co = 0; co < DIM_; ++co) acc[co] = b[co];
    for (int ci = 0; ci < CIN_; ++ci) {
        float v = xp[(size_t)ci * P_];
        #pragma unroll
        for (int co = 0; co < DIM_; ++co)
            acc[co] += v * w[co * CIN_ + ci];
    }
    float* op = out + (size_t)n * DIM_ * P_ + p;
    #pragma unroll
    for (int co = 0; co < DIM_; ++co) op[(size_t)co * P_] = acc[co];
}

// ---------------- per-channel sum / sumsq over [NC][S] slabs ---------------
__global__ __launch_bounds__(256) void stats_kernel(
        const float* __restrict__ in, int S,
        double* __restrict__ dsum, double* __restrict__ dsq) {
    int c = blockIdx.x & 31;
    const float* p = in + (size_t)blockIdx.x * S;
    double s = 0.0, q = 0.0;
    for (int i = threadIdx.x; i < S; i += 256) {
        double v = (double)p[i];
        s += v; q += v * v;
    }
    #pragma unroll
    for (int off = 32; off > 0; off >>= 1) {
        s += __shfl_down(s, off, 64);
        q += __shfl_down(q, off, 64);
    }
    __shared__ double ls[4], lq[4];
    int wv = threadIdx.x >> 6;
    if ((threadIdx.x & 63) == 0) { ls[wv] = s; lq[wv] = q; }
    __syncthreads();
    if (threadIdx.x == 0) {
        s = ls[0] + ls[1] + ls[2] + ls[3];
        q = lq[0] + lq[1] + lq[2] + lq[3];
        atomicAdd(&dsum[c], s);
        atomicAdd(&dsq[c], q);
    }
}

// ---------------- finalize BN: scale/shift per channel ---------------------
__global__ void fin_kernel(const double* __restrict__ dsum, const double* __restrict__ dsq,
                           const float* __restrict__ g, const float* __restrict__ be,
                           double cnt, float* __restrict__ scsh) {
    int c = threadIdx.x;
    if (c < 32) {
        double m = dsum[c] / cnt;
        double v = dsq[c] / cnt - m * m;
        double rstd = 1.0 / sqrt(v + 1e-5);
        double sc = (double)g[c] * rstd;
        scsh[c]      = (float)sc;
        scsh[32 + c] = (float)((double)be[c] - m * sc);
    }
}

// ---------------- DHT: feat(pre-BN) -> acc[n,c,192,192] --------------------
// grid (512, 3): one block per (n*32+c, angle-group of 64). LDS bins 48 KB.
__global__ __launch_bounds__(256) void dht_kernel(
        const float* __restrict__ feat, const unsigned char* __restrict__ lut,
        const float* __restrict__ scsh, float* __restrict__ acc) {
    __shared__ float bins[64][R_];            // 48 KB
    int nc = blockIdx.x, g = blockIdx.y;
    int c  = nc & 31;
    float sc = scsh[c], sh = scsh[32 + c];
    for (int i = threadIdx.x; i < 64 * R_; i += 256) ((float*)bins)[i] = 0.f;
    __syncthreads();

    const float4* fp = (const float4*)(feat + (size_t)nc * P_);
    for (int q = threadIdx.x; q < P_/4; q += 256) {
        float4 f = fp[q];
        f.x = fmaxf(f.x * sc + sh, 0.f);
        f.y = fmaxf(f.y * sc + sh, 0.f);
        f.z = fmaxf(f.z * sc + sh, 0.f);
        f.w = fmaxf(f.w * sc + sh, 0.f);
        const unsigned char* lp = lut + (size_t)(g * 64) * P_ + q * 4;
        #pragma unroll 4
        for (int a = 0; a < 64; ++a) {
            uchar4 r = *(const uchar4*)(lp + (size_t)a * P_);
            atomicAdd(&bins[a][r.x], f.x);
            atomicAdd(&bins[a][r.y], f.y);
            atomicAdd(&bins[a][r.z], f.z);
            atomicAdd(&bins[a][r.w], f.w);
        }
    }
    __syncthreads();
    float* ap = acc + (size_t)nc * AR_ + (size_t)(g * 64) * R_;
    for (int i = threadIdx.x; i < 64 * R_; i += 256) ap[i] = ((float*)bins)[i];
}

// ---------------- 3x3 conv (+optional input BN+ReLU) + bias ----------------
// grid (12,12,16), block 256 = 16x16 output tile, all 32 co per thread.
template <bool BN>
__global__ __launch_bounds__(256) void conv3x3_kernel(
        const float* __restrict__ in, const float* __restrict__ w,
        const float* __restrict__ b,
        const float* __restrict__ sc, const float* __restrict__ sh,
        float* __restrict__ out) {
    __shared__ float tile[18][20];
    int tx = threadIdx.x & 15, ty = threadIdx.x >> 4;
    int x0 = blockIdx.x * 16, y0 = blockIdx.y * 16, n = blockIdx.z;
    float acc[DIM_];
    #pragma unroll
    for (int co = 0; co < DIM_; ++co) acc[co] = b[co];

    for (int ci = 0; ci < DIM_; ++ci) {
        __syncthreads();
        const float* src = in + ((size_t)(n * DIM_ + ci)) * AR_;
        float csc = BN ? sc[ci] : 0.f, csh = BN ? sh[ci] : 0.f;
        for (int t = threadIdx.x; t < 18 * 18; t += 256) {
            int ly = t / 18, lx = t - ly * 18;
            int gy = y0 - 1 + ly, gx = x0 - 1 + lx;
            float v = 0.f;
            if (gy >= 0 && gy < 192 && gx >= 0 && gx < 192) {
                v = src[gy * 192 + gx];
                if (BN) v = fmaxf(v * csc + csh, 0.f);
            }
            tile[ly][lx] = v;
        }
        __syncthreads();
        float v[9];
        #pragma unroll
        for (int k = 0; k < 9; ++k) v[k] = tile[ty + k / 3][tx + k % 3];
        const float* wp = w + ci * 9;          // w[co][ci][k]: co stride 288
        #pragma unroll
        for (int co = 0; co < DIM_; ++co) {
            #pragma unroll
            for (int k = 0; k < 9; ++k)
                acc[co] += v[k] * wp[co * 288 + k];
        }
    }
    size_t o = ((size_t)(n * DIM_) * 192 + (y0 + ty)) * 192 + x0 + tx;
    #pragma unroll
    for (int co = 0; co < DIM_; ++co) out[o + (size_t)co * AR_] = acc[co];
}

// ---------------- final BN + ReLU -> d_out ---------------------------------
__global__ __launch_bounds__(256) void bnrelu_kernel(
        const float* __restrict__ in, const float* __restrict__ scsh,
        float* __restrict__ out) {
    int i = blockIdx.x * 256 + threadIdx.x;   // float4 index, total 4718592
    if (i >= 4718592) return;
    int c = (i / 9216) & 31;                  // 9216 float4 per channel slab
    float sc = scsh[c], sh = scsh[32 + c];
    float4 v = ((const float4*)in)[i];
    v.x = fmaxf(v.x * sc + sh, 0.f);
    v.y = fmaxf(v.y * sc + sh, 0.f);
    v.z = fmaxf(v.z * sc + sh, 0.f);
    v.w = fmaxf(v.w * sc + sh, 0.f);
    ((float4*)out)[i] = v;
}

extern "C" void kernel_launch(void* const* d_in, const int* in_sizes, int n_in,
                              void* d_out, int out_size, void* d_ws, size_t ws_size,
                              hipStream_t stream) {
    const float* x   = (const float*)d_in[0];
    const float* w1  = (const float*)d_in[1];
    const float* b1  = (const float*)d_in[2];
    const float* g1  = (const float*)d_in[3];
    const float* be1 = (const float*)d_in[4];
    const float* w2  = (const float*)d_in[5];
    const float* b2  = (const float*)d_in[6];
    const float* g2  = (const float*)d_in[7];
    const float* be2 = (const float*)d_in[8];
    const float* w3  = (const float*)d_in[9];
    const float* b3  = (const float*)d_in[10];
    const float* g3  = (const float*)d_in[11];
    const float* be3 = (const float*)d_in[12];
    float* out = (float*)d_out;

    char* ws = (char*)d_ws;
    float* bufA = (float*)(ws);                              // 75497472 B
    float* bufB = (float*)(ws + 75497472);                   // 75497472 B
    unsigned char* lut = (unsigned char*)(ws + 150994944);   // 3145728 B
    double* stats = (double*)(ws + 154140672);               // 192 doubles
    float*  scsh  = (float*)(ws + 154142208);                // 192 floats

    hipMemsetAsync(stats, 0, 192 * sizeof(double), stream);
    lut_kernel<<<192, 256, 0, stream>>>(lut);

    // stage 1: 1x1 conv -> bufA (pre-BN), stats, finalize
    conv1x1_kernel<<<1024, 256, 0, stream>>>(x, w1, b1, bufA);
    stats_kernel<<<512, 256, 0, stream>>>(bufA, P_, stats + 0, stats + 32);
    fin_kernel<<<1, 64, 0, stream>>>(stats + 0, stats + 32, g1, be1,
                                     (double)(N_ * P_), scsh);

    // stage 2: DHT (BN1+ReLU applied on the fly) -> bufB
    dht_kernel<<<dim3(512, 3), 256, 0, stream>>>(bufA, lut, scsh, bufB);

    // stage 3: conv2 (raw input) -> bufA, stats, finalize
    conv3x3_kernel<false><<<dim3(12, 12, 16), 256, 0, stream>>>(
        bufB, w2, b2, nullptr, nullptr, bufA);
    stats_kernel<<<512, 256, 0, stream>>>(bufA, AR_, stats + 64, stats + 96);
    fin_kernel<<<1, 64, 0, stream>>>(stats + 64, stats + 96, g2, be2,
                                     (double)(N_ * AR_), scsh + 64);

    // stage 4: conv3 (BN2+ReLU on the fly) -> bufB, stats, finalize
    conv3x3_kernel<true><<<dim3(12, 12, 16), 256, 0, stream>>>(
        bufA, w3, b3, scsh + 64, scsh + 96, bufB);
    stats_kernel<<<512, 256, 0, stream>>>(bufB, AR_, stats + 128, stats + 160);
    fin_kernel<<<1, 64, 0, stream>>>(stats + 128, stats + 160, g3, be3,
                                     (double)(N_ * AR_), scsh + 128);

    // epilogue: BN3 + ReLU -> out
    bnrelu_kernel<<<18432, 256, 0, stream>>>(bufB, scsh + 128, out);
}

// Round 2
// 2002.961 us; speedup vs baseline: 4.5937x; 4.5937x over previous
//
#include <hip/hip_runtime.h>
#include <math.h>

#define N_    16
#define CIN_  256
#define DIM_  32
#define H_    128
#define W_    128
#define P_    (H_*W_)          // 16384
#define A_    192
#define R_    192
#define AR_   (A_*R_)          // 36864
#define CSR_CAP 18432          // per-angle pixlist capacity (16384 + 192*3 pad, rounded)
#define FSLOT 16520            // per-channel LDS floats: 128*129=16512 data + zero slot @16512

// ---------------- CSR build: per-angle pixel lists sorted by rho -----------
// One block per angle. rho computed in fp64 exactly like np.round (rint).
// Segments padded to multiples of 4 with sentinel pixel 16384 (maps to LDS
// zero slot 16512 via addr = p + (p>>7)).
__global__ __launch_bounds__(256) void csr_build(
        unsigned short* __restrict__ pix, int* __restrict__ offg) {
    int a = blockIdx.x;
    __shared__ int cnt[192];
    __shared__ int off[193];
    __shared__ unsigned char rho_s[P_];       // 16 KB
    double theta = (double)a * (M_PI / 192.0);
    double irho  = 182.0 / 191.0;
    double ts = sin(theta) / irho;
    double tc = cos(theta) / irho;
    for (int i = threadIdx.x; i < 192; i += 256) cnt[i] = 0;
    __syncthreads();
    for (int p = threadIdx.x; p < P_; p += 256) {
        int y = p >> 7, x = p & 127;
        double v = __dadd_rn(__dmul_rn((double)(x - 64), tc),
                             __dmul_rn((double)(y - 64), ts));
        int r = (int)rint(v) + 96;
        r = r < 0 ? 0 : (r > 191 ? 191 : r);
        rho_s[p] = (unsigned char)r;
        atomicAdd(&cnt[r], 1);
    }
    __syncthreads();
    if (threadIdx.x == 0) {
        int run = 0;
        for (int r = 0; r < 192; ++r) { off[r] = run; run += (cnt[r] + 3) & ~3; }
        off[192] = run;
    }
    __syncthreads();
    if (threadIdx.x < 193) offg[a * 193 + threadIdx.x] = off[threadIdx.x];
    // reset cnt to running cursors
    for (int i = threadIdx.x; i < 192; i += 256) cnt[i] = off[i];
    __syncthreads();
    unsigned short* pa = pix + (size_t)a * CSR_CAP;
    for (int p = threadIdx.x; p < P_; p += 256) {
        int idx = atomicAdd(&cnt[rho_s[p]], 1);
        pa[idx] = (unsigned short)p;
    }
    __syncthreads();
    for (int r = threadIdx.x; r < 192; r += 256)
        for (int j = cnt[r]; j < off[r + 1]; ++j) pa[j] = 16384;  // sentinel
}

// ---------------- 1x1 conv + bias: x[16,256,128,128] -> pre[16,32,128,128] -
__global__ __launch_bounds__(256) void conv1x1_kernel(
        const float* __restrict__ x, const float* __restrict__ w,
        const float* __restrict__ b, float* __restrict__ out) {
    int g = blockIdx.x * 256 + threadIdx.x;   // 0..262143  (N*P)
    int n = g >> 14, p = g & (P_ - 1);
    const float* xp = x + (size_t)n * CIN_ * P_ + p;
    float acc[DIM_];
    #pragma unroll
    for (int co = 0; co < DIM_; ++co) acc[co] = b[co];
    for (int ci = 0; ci < CIN_; ++ci) {
        float v = xp[(size_t)ci * P_];
        #pragma unroll
        for (int co = 0; co < DIM_; ++co)
            acc[co] += v * w[co * CIN_ + ci];
    }
    float* op = out + (size_t)n * DIM_ * P_ + p;
    #pragma unroll
    for (int co = 0; co < DIM_; ++co) op[(size_t)co * P_] = acc[co];
}

// ---------------- per-channel sum / sumsq over [NC][S] slabs ---------------
__global__ __launch_bounds__(256) void stats_kernel(
        const float* __restrict__ in, int S,
        double* __restrict__ dsum, double* __restrict__ dsq) {
    int c = blockIdx.x & 31;
    const float* p = in + (size_t)blockIdx.x * S;
    double s = 0.0, q = 0.0;
    for (int i = threadIdx.x; i < S; i += 256) {
        double v = (double)p[i];
        s += v; q += v * v;
    }
    #pragma unroll
    for (int off = 32; off > 0; off >>= 1) {
        s += __shfl_down(s, off, 64);
        q += __shfl_down(q, off, 64);
    }
    __shared__ double ls[4], lq[4];
    int wv = threadIdx.x >> 6;
    if ((threadIdx.x & 63) == 0) { ls[wv] = s; lq[wv] = q; }
    __syncthreads();
    if (threadIdx.x == 0) {
        s = ls[0] + ls[1] + ls[2] + ls[3];
        q = lq[0] + lq[1] + lq[2] + lq[3];
        atomicAdd(&dsum[c], s);
        atomicAdd(&dsq[c], q);
    }
}

// ---------------- finalize BN: scale/shift per channel ---------------------
__global__ void fin_kernel(const double* __restrict__ dsum, const double* __restrict__ dsq,
                           const float* __restrict__ g, const float* __restrict__ be,
                           double cnt, float* __restrict__ scsh) {
    int c = threadIdx.x;
    if (c < 32) {
        double m = dsum[c] / cnt;
        double v = dsq[c] / cnt - m * m;
        double rstd = 1.0 / sqrt(v + 1e-5);
        double sc = (double)g[c] * rstd;
        scsh[c]      = (float)sc;
        scsh[32 + c] = (float)((double)be[c] - m * sc);
    }
}

// ---------------- DHT gather: feat(pre-BN) -> acc[n,c,192,192] -------------
// 256 blocks x 384 threads. Each block stages 2 channels in LDS (swizzled
// stride-129: addr = p + (p>>7)), then threads (da=tid/192, r=tid%192) sum
// CSR segments for both channels at once (one pixlist read, two ds_reads).
__global__ __launch_bounds__(384) void dht_gather(
        const float* __restrict__ feat, const unsigned short* __restrict__ pix,
        const int* __restrict__ offg, const float* __restrict__ scsh,
        float* __restrict__ acc) {
    extern __shared__ float feat2[];          // 2 * FSLOT floats = 132160 B
    int nc0 = blockIdx.x * 2;
    #pragma unroll
    for (int ncl = 0; ncl < 2; ++ncl) {
        int c = (nc0 + ncl) & 31;
        float sc = scsh[c], sh = scsh[32 + c];
        const float4* fp = (const float4*)(feat + (size_t)(nc0 + ncl) * P_);
        float* dst = feat2 + ncl * FSLOT;
        for (int q = threadIdx.x; q < P_ / 4; q += 384) {
            float4 f = fp[q];
            int p = q * 4;
            int base = p + (p >> 7);          // y*129 + x
            dst[base + 0] = fmaxf(f.x * sc + sh, 0.f);
            dst[base + 1] = fmaxf(f.y * sc + sh, 0.f);
            dst[base + 2] = fmaxf(f.z * sc + sh, 0.f);
            dst[base + 3] = fmaxf(f.w * sc + sh, 0.f);
        }
        if (threadIdx.x < 8) dst[16512 + threadIdx.x] = 0.f;  // sentinel slots
    }
    __syncthreads();
    int da = threadIdx.x / 192, r = threadIdx.x % 192;
    for (int ap = 0; ap < 96; ++ap) {
        int a = ap * 2 + da;
        int o0 = offg[a * 193 + r];
        int o1 = offg[a * 193 + r + 1];
        const unsigned short* pl = pix + (size_t)a * CSR_CAP;
        float s0 = 0.f, s1 = 0.f;
        int j = o0;
        for (; j + 8 <= o1; j += 8) {
            ushort4 ua = *(const ushort4*)(pl + j);
            ushort4 ub = *(const ushort4*)(pl + j + 4);
            int p0 = ua.x, p1 = ua.y, p2 = ua.z, p3 = ua.w;
            int p4 = ub.x, p5 = ub.y, p6 = ub.z, p7 = ub.w;
            int a0 = p0 + (p0 >> 7), a1 = p1 + (p1 >> 7);
            int a2 = p2 + (p2 >> 7), a3 = p3 + (p3 >> 7);
            int a4 = p4 + (p4 >> 7), a5 = p5 + (p5 >> 7);
            int a6 = p6 + (p6 >> 7), a7 = p7 + (p7 >> 7);
            s0 += feat2[a0]; s1 += feat2[a0 + FSLOT];
            s0 += feat2[a1]; s1 += feat2[a1 + FSLOT];
            s0 += feat2[a2]; s1 += feat2[a2 + FSLOT];
            s0 += feat2[a3]; s1 += feat2[a3 + FSLOT];
            s0 += feat2[a4]; s1 += feat2[a4 + FSLOT];
            s0 += feat2[a5]; s1 += feat2[a5 + FSLOT];
            s0 += feat2[a6]; s1 += feat2[a6 + FSLOT];
            s0 += feat2[a7]; s1 += feat2[a7 + FSLOT];
        }
        if (j < o1) {                          // padded: remainder is exactly 4
            ushort4 ua = *(const ushort4*)(pl + j);
            int p0 = ua.x, p1 = ua.y, p2 = ua.z, p3 = ua.w;
            int a0 = p0 + (p0 >> 7), a1 = p1 + (p1 >> 7);
            int a2 = p2 + (p2 >> 7), a3 = p3 + (p3 >> 7);
            s0 += feat2[a0]; s1 += feat2[a0 + FSLOT];
            s0 += feat2[a1]; s1 += feat2[a1 + FSLOT];
            s0 += feat2[a2]; s1 += feat2[a2 + FSLOT];
            s0 += feat2[a3]; s1 += feat2[a3 + FSLOT];
        }
        size_t ob = (size_t)nc0 * AR_ + (size_t)a * R_ + r;
        acc[ob] = s0;
        acc[ob + AR_] = s1;
    }
}

// ---------------- 3x3 conv (+optional input BN+ReLU) + bias ----------------
template <bool BN>
__global__ __launch_bounds__(256) void conv3x3_kernel(
        const float* __restrict__ in, const float* __restrict__ w,
        const float* __restrict__ b,
        const float* __restrict__ sc, const float* __restrict__ sh,
        float* __restrict__ out) {
    __shared__ float tile[18][20];
    int tx = threadIdx.x & 15, ty = threadIdx.x >> 4;
    int x0 = blockIdx.x * 16, y0 = blockIdx.y * 16, n = blockIdx.z;
    float acc[DIM_];
    #pragma unroll
    for (int co = 0; co < DIM_; ++co) acc[co] = b[co];

    for (int ci = 0; ci < DIM_; ++ci) {
        __syncthreads();
        const float* src = in + ((size_t)(n * DIM_ + ci)) * AR_;
        float csc = BN ? sc[ci] : 0.f, csh = BN ? sh[ci] : 0.f;
        for (int t = threadIdx.x; t < 18 * 18; t += 256) {
            int ly = t / 18, lx = t - ly * 18;
            int gy = y0 - 1 + ly, gx = x0 - 1 + lx;
            float v = 0.f;
            if (gy >= 0 && gy < 192 && gx >= 0 && gx < 192) {
                v = src[gy * 192 + gx];
                if (BN) v = fmaxf(v * csc + csh, 0.f);
            }
            tile[ly][lx] = v;
        }
        __syncthreads();
        float v[9];
        #pragma unroll
        for (int k = 0; k < 9; ++k) v[k] = tile[ty + k / 3][tx + k % 3];
        const float* wp = w + ci * 9;          // w[co][ci][k]: co stride 288
        #pragma unroll
        for (int co = 0; co < DIM_; ++co) {
            #pragma unroll
            for (int k = 0; k < 9; ++k)
                acc[co] += v[k] * wp[co * 288 + k];
        }
    }
    size_t o = ((size_t)(n * DIM_) * 192 + (y0 + ty)) * 192 + x0 + tx;
    #pragma unroll
    for (int co = 0; co < DIM_; ++co) out[o + (size_t)co * AR_] = acc[co];
}

// ---------------- final BN + ReLU -> d_out ---------------------------------
__global__ __launch_bounds__(256) void bnrelu_kernel(
        const float* __restrict__ in, const float* __restrict__ scsh,
        float* __restrict__ out) {
    int i = blockIdx.x * 256 + threadIdx.x;   // float4 index, total 4718592
    if (i >= 4718592) return;
    int c = (i / 9216) & 31;                  // 9216 float4 per channel slab
    float sc = scsh[c], sh = scsh[32 + c];
    float4 v = ((const float4*)in)[i];
    v.x = fmaxf(v.x * sc + sh, 0.f);
    v.y = fmaxf(v.y * sc + sh, 0.f);
    v.z = fmaxf(v.z * sc + sh, 0.f);
    v.w = fmaxf(v.w * sc + sh, 0.f);
    ((float4*)out)[i] = v;
}

extern "C" void kernel_launch(void* const* d_in, const int* in_sizes, int n_in,
                              void* d_out, int out_size, void* d_ws, size_t ws_size,
                              hipStream_t stream) {
    const float* x   = (const float*)d_in[0];
    const float* w1  = (const float*)d_in[1];
    const float* b1  = (const float*)d_in[2];
    const float* g1  = (const float*)d_in[3];
    const float* be1 = (const float*)d_in[4];
    const float* w2  = (const float*)d_in[5];
    const float* b2  = (const float*)d_in[6];
    const float* g2  = (const float*)d_in[7];
    const float* be2 = (const float*)d_in[8];
    const float* w3  = (const float*)d_in[9];
    const float* b3  = (const float*)d_in[10];
    const float* g3  = (const float*)d_in[11];
    const float* be3 = (const float*)d_in[12];
    float* out = (float*)d_out;

    char* ws = (char*)d_ws;
    float* bufA = (float*)(ws);                       // [0, 75497472)
    //   conv1 out uses [0, 33554432); CSR lives in the tail (dead once conv2 runs)
    unsigned short* pix = (unsigned short*)(ws + 33554432);   // 7,077,888 B
    int*   offg  = (int*)(ws + 40632320);                     // 148,224 B
    float* bufB  = (float*)(ws + 75497472);                   // 75,497,472 B
    double* stats = (double*)(ws + 150994944);                // 1536 B
    float*  scsh  = (float*)(ws + 150996480);                 // 768 B

    hipMemsetAsync(stats, 0, 192 * sizeof(double), stream);
    csr_build<<<192, 256, 0, stream>>>(pix, offg);

    // stage 1: 1x1 conv -> bufA (pre-BN), stats, finalize
    conv1x1_kernel<<<1024, 256, 0, stream>>>(x, w1, b1, bufA);
    stats_kernel<<<512, 256, 0, stream>>>(bufA, P_, stats + 0, stats + 32);
    fin_kernel<<<1, 64, 0, stream>>>(stats + 0, stats + 32, g1, be1,
                                     (double)(N_ * P_), scsh);

    // stage 2: DHT gather (BN1+ReLU applied while staging to LDS) -> bufB
    hipFuncSetAttribute((const void*)dht_gather,
                        hipFuncAttributeMaxDynamicSharedMemorySize,
                        2 * FSLOT * sizeof(float));
    dht_gather<<<256, 384, 2 * FSLOT * sizeof(float), stream>>>(
        bufA, pix, offg, scsh, bufB);

    // stage 3: conv2 (raw input) -> bufA, stats, finalize
    conv3x3_kernel<false><<<dim3(12, 12, 16), 256, 0, stream>>>(
        bufB, w2, b2, nullptr, nullptr, bufA);
    stats_kernel<<<512, 256, 0, stream>>>(bufA, AR_, stats + 64, stats + 96);
    fin_kernel<<<1, 64, 0, stream>>>(stats + 64, stats + 96, g2, be2,
                                     (double)(N_ * AR_), scsh + 64);

    // stage 4: conv3 (BN2+ReLU on the fly) -> bufB, stats, finalize
    conv3x3_kernel<true><<<dim3(12, 12, 16), 256, 0, stream>>>(
        bufA, w3, b3, scsh + 64, scsh + 96, bufB);
    stats_kernel<<<512, 256, 0, stream>>>(bufB, AR_, stats + 128, stats + 160);
    fin_kernel<<<1, 64, 0, stream>>>(stats + 128, stats + 160, g3, be3,
                                     (double)(N_ * AR_), scsh + 128);

    // epilogue: BN3 + ReLU -> out
    bnrelu_kernel<<<18432, 256, 0, stream>>>(bufB, scsh + 128, out);
}